// Round 1
// 1387.733 us; speedup vs baseline: 1.0063x; 1.0063x over previous
//
#include <hip/hip_runtime.h>
#include <math.h>

// ---------------------------------------------------------------------------
// Llama3-8B decode attention, fp32. B=128, H=4096, L=1024, 32 q heads,
// 8 kv heads (GQA rep=4), head_dim=128.
// Key simplification: k_new / wk are DEAD CODE in the reference (softmax over
// a length-1 axis is identically 1.0), so new_out == v_new. We never read wk.
// Pipeline: rmsnorm -> rope vector -> [q|v] GEMM (rope fused) -> attention
// (+v_new fused) -> output GEMM.
//
// R1: attention rewritten as a streaming kernel. K and V are never staged in
// LDS (the old sK[64][132] layout was an 8-way bank conflict and both passes
// were LDS-pipe-bound). Pass 1 uses a d-split (8 lanes/key) with q held in
// registers and shfl_xor reduction; pass 2 streams V rows directly from
// global (one contiguous 512B row per wave instruction), P broadcast from
// LDS. One barrier total; LDS 52KB -> 16KB.
// ---------------------------------------------------------------------------

#define THREADS 256

__global__ __launch_bounds__(256) void rmsnorm_kernel(
    const float* __restrict__ x, const float* __restrict__ w,
    float* __restrict__ xn, int H) {
  int b = blockIdx.x;
  int t = threadIdx.x;
  const float4* x4 = (const float4*)(x + (size_t)b * H);
  const float4* w4 = (const float4*)w;
  float4* y4 = (float4*)(xn + (size_t)b * H);
  int n4 = H >> 2;
  float ss = 0.f;
  for (int i = t; i < n4; i += THREADS) {
    float4 v = x4[i];
    ss += v.x * v.x + v.y * v.y + v.z * v.z + v.w * v.w;
  }
#pragma unroll
  for (int off = 32; off; off >>= 1) ss += __shfl_xor(ss, off, 64);
  __shared__ float red[4];
  if ((t & 63) == 0) red[t >> 6] = ss;
  __syncthreads();
  float tot = red[0] + red[1] + red[2] + red[3];
  float rs = rsqrtf(tot / (float)H + 1e-5f);
  for (int i = t; i < n4; i += THREADS) {
    float4 v = x4[i];
    float4 g = w4[i];
    float4 o;
    o.x = v.x * rs * g.x;
    o.y = v.y * rs * g.y;
    o.z = v.z * rs * g.z;
    o.w = v.w * rs * g.w;
    y4[i] = o;
  }
}

// rope[d] = cos(a) - sin(a) for d<64, cos(a) + sin(a) for d>=64,
// a = L * theta^(-(d&63)/128). Double precision to match numpy float64.
__global__ void rope_kernel(float* __restrict__ rope, int L) {
  int d = threadIdx.x;  // 128 threads
  int i = d & 63;
  double ang = (double)L * pow(500000.0, -((double)i) / 128.0);
  double c = cos(ang), s = sin(ang);
  rope[d] = (float)(d < 64 ? c - s : c + s);
}

// Y[M x (n1+n2)] = X[M x K] @ [W1 | W2]; 32x32 tile per block, 256 threads,
// each thread: 1 row x 4 cols. Columns < n1 optionally scaled by
// rope[(globalcol)&127] (the q path); columns >= n1 go to Y2 (the v path).
__global__ __launch_bounds__(256) void gemm32(
    const float* __restrict__ X, int K,
    const float* __restrict__ W1, int n1,
    const float* __restrict__ W2, int n2,
    const float* __restrict__ rope,
    float* __restrict__ Y1, float* __restrict__ Y2) {
  __shared__ float xs[32][36];   // +pad: rows land on distinct bank groups
  __shared__ float wsh[32][36];
  int t = threadIdx.x;
  int colOff = blockIdx.x * 32;
  int rowOff = blockIdx.y * 32;
  bool reg2 = (colOff >= n1);
  const float* W = reg2 ? W2 : W1;
  int ld = reg2 ? n2 : n1;
  int c0 = reg2 ? colOff - n1 : colOff;
  int lr = t >> 3;   // 0..31: load row (X) / load k-row (W) / compute row
  int lc4 = t & 7;   // 0..7: f4 slot on load; col group on compute
  float4 acc = make_float4(0.f, 0.f, 0.f, 0.f);
  for (int kc = 0; kc < K; kc += 32) {
    float4 xv = *(const float4*)(X + (size_t)(rowOff + lr) * K + kc + lc4 * 4);
    float4 wv = *(const float4*)(W + (size_t)(kc + lr) * ld + c0 + lc4 * 4);
    xs[lr][lc4 * 4 + 0] = xv.x;
    xs[lr][lc4 * 4 + 1] = xv.y;
    xs[lr][lc4 * 4 + 2] = xv.z;
    xs[lr][lc4 * 4 + 3] = xv.w;
    *(float4*)(&wsh[lr][lc4 * 4]) = wv;
    __syncthreads();
#pragma unroll
    for (int k = 0; k < 32; k += 4) {
      float4 xq = *(const float4*)(&xs[lr][k]);
#pragma unroll
      for (int kk = 0; kk < 4; kk++) {
        float4 wq4 = *(const float4*)(&wsh[k + kk][lc4 * 4]);
        float xsc = (&xq.x)[kk];
        acc.x += xsc * wq4.x;
        acc.y += xsc * wq4.y;
        acc.z += xsc * wq4.z;
        acc.w += xsc * wq4.w;
      }
    }
    __syncthreads();
  }
  float4 o = acc;
  if (!reg2 && rope != nullptr) {
    float4 rp = *(const float4*)(rope + ((colOff + lc4 * 4) & 127));
    o.x *= rp.x;
    o.y *= rp.y;
    o.z *= rp.z;
    o.w *= rp.w;
  }
  float* Y = reg2 ? Y2 : Y1;
  *(float4*)(Y + (size_t)(rowOff + lr) * ld + c0 + lc4 * 4) = o;
}

// One block per (b, kv-head g). 256 threads = 4 waves.
// Pass 1 (scores): d-split. Each wave handles 8 keys/iter; within a key, 8
// lanes each own 16 dims laid out as 4 float4s at d = li*4 + j*32, so every
// global load instruction covers 8 keys x 128B = 1KB contiguous. q lives in
// registers (16 float4/thread, all 4 reps). 3-step shfl_xor reduce over the
// 8 lanes, then lanes li<4 write rep li's score to sS.
// Softmax: per-wave (wave == rep) over L, as before.
// Pass 2 (O = P @ V): thread (r = wave, d0 = lane*2) streams V directly from
// global; one wave instruction = one contiguous 512B V row (L1/L2 absorb the
// 4x cross-wave re-read). P read as wave-uniform float4 broadcasts from sS.
// No K/V LDS staging, a single __syncthreads, LDS = 16KB.
__global__ __launch_bounds__(256) void attn_kernel(
    const float* __restrict__ q, const float* __restrict__ kc_,
    const float* __restrict__ vc_, const float* __restrict__ vnew,
    float* __restrict__ ho, int L) {
  __shared__ float sS[4][1024];   // scores/probs, rows = rep heads
  int t = threadIdx.x;
  int b = blockIdx.x >> 3;
  int g = blockIdx.x & 7;
  int w = t >> 6;      // wave id
  int l = t & 63;      // lane
  int li = l & 7;      // lane-in-key (d-split slot)
  int kg = l >> 3;     // key-in-group (8 keys per wave iter)
  const float scale = 0.08838834764831845f;  // 1/sqrt(128)

  // q fragments: qf[r][j] = q[b][g*4+r][li*4 + j*32 .. +3]
  const float* qbase = q + (size_t)b * 4096 + (size_t)g * 512;
  float4 qf[4][4];
#pragma unroll
  for (int r = 0; r < 4; r++)
#pragma unroll
    for (int j = 0; j < 4; j++)
      qf[r][j] = *(const float4*)(qbase + r * 128 + li * 4 + j * 32);

  // ---- pass 1: scores ----
  const float* kbase = kc_ + (size_t)(b * 8 + g) * (size_t)L * 128;
  int nIter = L >> 5;  // 32 keys per iter across the 4 waves
#pragma unroll 2
  for (int it = 0; it < nIter; ++it) {
    int key = it * 32 + w * 8 + kg;
    const float4* kp = (const float4*)(kbase + (size_t)key * 128);
    float4 k0 = kp[li];
    float4 k1 = kp[li + 8];
    float4 k2 = kp[li + 16];
    float4 k3 = kp[li + 24];
    float s0, s1, s2, s3;
    {
      float4 a = qf[0][0], bq = qf[0][1], c = qf[0][2], d = qf[0][3];
      s0 = k0.x * a.x + k0.y * a.y + k0.z * a.z + k0.w * a.w
         + k1.x * bq.x + k1.y * bq.y + k1.z * bq.z + k1.w * bq.w
         + k2.x * c.x + k2.y * c.y + k2.z * c.z + k2.w * c.w
         + k3.x * d.x + k3.y * d.y + k3.z * d.z + k3.w * d.w;
    }
    {
      float4 a = qf[1][0], bq = qf[1][1], c = qf[1][2], d = qf[1][3];
      s1 = k0.x * a.x + k0.y * a.y + k0.z * a.z + k0.w * a.w
         + k1.x * bq.x + k1.y * bq.y + k1.z * bq.z + k1.w * bq.w
         + k2.x * c.x + k2.y * c.y + k2.z * c.z + k2.w * c.w
         + k3.x * d.x + k3.y * d.y + k3.z * d.z + k3.w * d.w;
    }
    {
      float4 a = qf[2][0], bq = qf[2][1], c = qf[2][2], d = qf[2][3];
      s2 = k0.x * a.x + k0.y * a.y + k0.z * a.z + k0.w * a.w
         + k1.x * bq.x + k1.y * bq.y + k1.z * bq.z + k1.w * bq.w
         + k2.x * c.x + k2.y * c.y + k2.z * c.z + k2.w * c.w
         + k3.x * d.x + k3.y * d.y + k3.z * d.z + k3.w * d.w;
    }
    {
      float4 a = qf[3][0], bq = qf[3][1], c = qf[3][2], d = qf[3][3];
      s3 = k0.x * a.x + k0.y * a.y + k0.z * a.z + k0.w * a.w
         + k1.x * bq.x + k1.y * bq.y + k1.z * bq.z + k1.w * bq.w
         + k2.x * c.x + k2.y * c.y + k2.z * c.z + k2.w * c.w
         + k3.x * d.x + k3.y * d.y + k3.z * d.z + k3.w * d.w;
    }
#pragma unroll
    for (int off = 1; off < 8; off <<= 1) {
      s0 += __shfl_xor(s0, off, 64);
      s1 += __shfl_xor(s1, off, 64);
      s2 += __shfl_xor(s2, off, 64);
      s3 += __shfl_xor(s3, off, 64);
    }
    if (li == 0)      sS[0][key] = s0 * scale;
    else if (li == 1) sS[1][key] = s1 * scale;
    else if (li == 2) sS[2][key] = s2 * scale;
    else if (li == 3) sS[3][key] = s3 * scale;
  }
  __syncthreads();   // all waves wrote all rep rows

  // ---- softmax over L, one wave per rep (wave reads/writes only row w) ----
  int r = w;
  float m = -INFINITY;
  for (int i = l; i < L; i += 64) m = fmaxf(m, sS[r][i]);
#pragma unroll
  for (int off = 32; off; off >>= 1) m = fmaxf(m, __shfl_xor(m, off, 64));
  float sum = 0.f;
  for (int i = l; i < L; i += 64) {
    float e = __expf(sS[r][i] - m);
    sS[r][i] = e;
    sum += e;
  }
#pragma unroll
  for (int off = 32; off; off >>= 1) sum += __shfl_xor(sum, off, 64);
  float inv = 1.f / sum;
  for (int i = l; i < L; i += 64) sS[r][i] *= inv;
  // no barrier: pass 2 reads only row r, written by this wave

  // ---- pass 2: O = P @ V, streamed from global ----
  int d0 = l * 2;
  float acc0 = 0.f, acc1 = 0.f;
  const float* vbase = vc_ + (size_t)(b * 8 + g) * (size_t)L * 128;
#pragma unroll 4
  for (int ll4 = 0; ll4 < L; ll4 += 4) {
    float4 p4 = *(const float4*)(&sS[r][ll4]);   // wave-uniform broadcast
    const float* v0 = vbase + (size_t)ll4 * 128 + d0;
    float2 va = *(const float2*)(v0);
    float2 vb = *(const float2*)(v0 + 128);
    float2 vc2 = *(const float2*)(v0 + 256);
    float2 vd = *(const float2*)(v0 + 384);
    acc0 += p4.x * va.x + p4.y * vb.x + p4.z * vc2.x + p4.w * vd.x;
    acc1 += p4.x * va.y + p4.y * vb.y + p4.z * vc2.y + p4.w * vd.y;
  }
  float2 vn = *(const float2*)(vnew + (size_t)b * 1024 + (size_t)g * 128 + d0);
  float2 o;
  o.x = acc0 + vn.x;
  o.y = acc1 + vn.y;
  *(float2*)(ho + (size_t)b * 4096 + (size_t)(g * 4 + r) * 128 + d0) = o;
}

extern "C" void kernel_launch(void* const* d_in, const int* in_sizes, int n_in,
                              void* d_out, int out_size, void* d_ws, size_t ws_size,
                              hipStream_t stream) {
  const float* x = (const float*)d_in[0];
  const float* kcache = (const float*)d_in[1];
  const float* vcache = (const float*)d_in[2];
  const float* normw = (const float*)d_in[3];
  const float* wq = (const float*)d_in[4];
  // d_in[5] (wk) intentionally unused: dead code in the reference.
  const float* wv = (const float*)d_in[6];
  const float* wo = (const float*)d_in[7];
  float* out = (float*)d_out;

  int H = in_sizes[3];                       // 4096
  int B = in_sizes[0] / H;                   // 128
  int Dq = in_sizes[4] / H;                  // 4096 = 32 heads * 128
  int Dv = in_sizes[6] / H;                  // 1024 = 8 kv heads * 128
  long long L = (long long)in_sizes[1] / ((long long)B * Dv);  // 1024

  // workspace layout (floats): xn | rope | q | vnew | ho  (~6.8 MB total)
  float* xn = (float*)d_ws;
  float* rope = xn + (size_t)B * H;
  float* qws = rope + 128;
  float* vnew = qws + (size_t)B * Dq;
  float* ho = vnew + (size_t)B * Dv;

  rmsnorm_kernel<<<B, 256, 0, stream>>>(x, normw, xn, H);
  rope_kernel<<<1, 128, 0, stream>>>(rope, (int)L);
  gemm32<<<dim3((Dq + Dv) / 32, B / 32), 256, 0, stream>>>(
      xn, H, wq, Dq, wv, Dv, rope, qws, vnew);
  attn_kernel<<<B * 8, 256, 0, stream>>>(qws, kcache, vcache, vnew, ho, (int)L);
  gemm32<<<dim3(H / 32, B / 32), 256, 0, stream>>>(
      ho, Dq, wo, H, nullptr, 0, nullptr, out, nullptr);
}